// Round 3
// baseline (1997.529 us; speedup 1.0000x reference)
//
#include <hip/hip_runtime.h>

using bf16x8 = __attribute__((ext_vector_type(8))) short;
using f32x4  = __attribute__((ext_vector_type(4))) float;
using us4    = __attribute__((ext_vector_type(4))) unsigned short;
using u32x2  = __attribute__((ext_vector_type(2))) unsigned int;

__device__ __forceinline__ unsigned short f2bf(float f) {
    unsigned int u = __builtin_bit_cast(unsigned int, f);
    u += 0x7fffu + ((u >> 16) & 1u);   // RNE
    return (unsigned short)(u >> 16);
}
__device__ __forceinline__ float bf2f(unsigned short s) {
    unsigned int u = ((unsigned int)s) << 16;
    return __builtin_bit_cast(float, u);
}
// packed f32x2 -> bf16x2 (RNE), single VALU inst (HW-proven: learn_hip m214v22)
__device__ __forceinline__ unsigned int cvt_pk_bf16(float a, float b) {
    unsigned int r;
    asm("v_cvt_pk_bf16_f32 %0, %1, %2" : "=v"(r) : "v"(a), "v"(b));
    return r;
}

// ---------------------------------------------------------------------------
// NT GEMM: Out[M,N] = A[M,K] @ B[N,K]^T (+bias (+addend)) * scale
// M=8192, N=1024, K=1024. 128x128 tile, BK=64, 256 threads (4 waves, 2x2).
// ---------------------------------------------------------------------------
template<int A_BF16, int OUT_FP32>
__global__ __launch_bounds__(256, 3)
void gemm_nt_kernel(const void* __restrict__ Ap, const float* __restrict__ Bp,
                    const float* __restrict__ bias,
                    const unsigned short* __restrict__ addend,
                    void* __restrict__ Outp, float scale)
{
    constexpr int LDA = 72;  // bf16 elems per LDS row (144 B: 16B-aligned)
    __shared__ unsigned short As[128 * LDA];
    __shared__ unsigned short Bs[128 * LDA];

    const int tid = threadIdx.x;
    const int bn = blockIdx.x, bm = blockIdx.y;
    const int wid = tid >> 6, lane = tid & 63;
    const int qd = lane >> 4, ln = lane & 15;
    const int wm = (wid >> 1) * 64, wn = (wid & 1) * 64;

    f32x4 zero4 = {0.f, 0.f, 0.f, 0.f};
    f32x4 acc[4][4];
#pragma unroll
    for (int i = 0; i < 4; ++i)
#pragma unroll
        for (int j = 0; j < 4; ++j) acc[i][j] = zero4;

    const float* Af = (const float*)Ap;
    const unsigned short* Ab = (const unsigned short*)Ap;

    for (int kk = 0; kk < 1024; kk += 64) {
        // ---- stage A tile (128 x 64) ----
        if (A_BF16) {
#pragma unroll
            for (int it = 0; it < 4; ++it) {
                int idx = tid + it * 256;           // 1024 chunks of 8 bf16
                int r = idx >> 3, c8 = idx & 7;
                uint4 v = *(const uint4*)(Ab + (size_t)(bm * 128 + r) * 1024 + kk + c8 * 8);
                *(uint4*)(As + r * LDA + c8 * 8) = v;
            }
        } else {
#pragma unroll
            for (int it = 0; it < 8; ++it) {
                int idx = tid + it * 256;           // 2048 float4
                int r = idx >> 4, c4 = idx & 15;
                float4 v = *(const float4*)(Af + (size_t)(bm * 128 + r) * 1024 + kk + c4 * 4);
                u32x2 o = { cvt_pk_bf16(v.x, v.y), cvt_pk_bf16(v.z, v.w) };
                *(u32x2*)(As + r * LDA + c4 * 4) = o;
            }
        }
        // ---- stage B tile (128 x 64), always fp32 weights ----
#pragma unroll
        for (int it = 0; it < 8; ++it) {
            int idx = tid + it * 256;
            int r = idx >> 4, c4 = idx & 15;
            float4 v = *(const float4*)(Bp + (size_t)(bn * 128 + r) * 1024 + kk + c4 * 4);
            u32x2 o = { cvt_pk_bf16(v.x, v.y), cvt_pk_bf16(v.z, v.w) };
            *(u32x2*)(Bs + r * LDA + c4 * 4) = o;
        }
        __syncthreads();

#pragma unroll
        for (int ks = 0; ks < 2; ++ks) {
            bf16x8 af[4], bfr[4];
#pragma unroll
            for (int i = 0; i < 4; ++i)
                af[i] = *(const bf16x8*)(As + (wm + i * 16 + ln) * LDA + ks * 32 + qd * 8);
#pragma unroll
            for (int i = 0; i < 4; ++i)
                bfr[i] = *(const bf16x8*)(Bs + (wn + i * 16 + ln) * LDA + ks * 32 + qd * 8);
#pragma unroll
            for (int mi = 0; mi < 4; ++mi)
#pragma unroll
                for (int ni = 0; ni < 4; ++ni)
                    acc[mi][ni] = __builtin_amdgcn_mfma_f32_16x16x32_bf16(
                        af[mi], bfr[ni], acc[mi][ni], 0, 0, 0);
        }
        __syncthreads();
    }

    // ---- epilogue ----
#pragma unroll
    for (int mi = 0; mi < 4; ++mi) {
#pragma unroll
        for (int ni = 0; ni < 4; ++ni) {
            int ocol = bn * 128 + wn + ni * 16 + ln;
            float bv = bias[ocol];
#pragma unroll
            for (int r = 0; r < 4; ++r) {
                int orow = bm * 128 + wm + mi * 16 + qd * 4 + r;
                float v = acc[mi][ni][r] + bv;
                if (OUT_FP32) {
                    ((float*)Outp)[(size_t)orow * 1024 + ocol] = v;
                } else {
                    int b = orow >> 11, l = orow & 2047;
                    int h = ocol >> 6, dk = ocol & 63;
                    size_t oidx = ((size_t)(b * 16 + h) * 2048 + l) * 64 + dk;
                    if (addend) v += bf2f(addend[oidx]);
                    v *= scale;
                    ((unsigned short*)Outp)[oidx] = f2bf(v);
                }
            }
        }
    }
}

// ---------------------------------------------------------------------------
// Fused two-pass attention. Grid: (16 q-tiles, 64 b*h). 256 thr, 4 waves.
// qh is pre-scaled by log2(e)/sqrt(DK) -> softmax uses exp2 directly, no max
// subtraction needed (|S| <= ~5 in exp2 domain, fp32-safe).
// Pass1: per-lane partial row sums, one cross-lane reduce at the end.
// Pass2: P~ = exp2(s)*keep -> Ps (bf16, unnormalized); attn = P~ * (1/l)
// written fp32 straight from regs; O = (P~ @ V) * (1/l) at epilogue.
// ---------------------------------------------------------------------------
__global__ __launch_bounds__(256, 2)
void attn_kernel(const unsigned short* __restrict__ qh,
                 const unsigned short* __restrict__ kh,
                 const unsigned short* __restrict__ vh,
                 const int* __restrict__ mask,
                 float* __restrict__ attn,
                 unsigned short* __restrict__ Og)
{
    constexpr int LKS = 72;    // K tile: [128][64] + pad
    constexpr int LVS = 136;   // V^T tile: [64][128] + pad
    constexpr int LPS = 136;   // P tile: [128][128] + pad
    __shared__ unsigned short Ks[128 * LKS];
    __shared__ unsigned short Vts[64 * LVS];
    __shared__ unsigned short Ps[128 * LPS];

    const int tid = threadIdx.x;
    const int qt = blockIdx.x;   // q tile 0..15
    const int bh = blockIdx.y;   // 0..63
    const int b = bh >> 4, h = bh & 15;
    const int wid = tid >> 6, lane = tid & 63;
    const int qd = lane >> 4, ln = lane & 15;

    const size_t head_off = (size_t)bh * 2048 * 64;
    const unsigned short* qbase = qh + head_off + (size_t)(qt * 128 + wid * 32) * 64;
    const unsigned short* kbase = kh + head_off;
    const unsigned short* vbase = vh + head_off;
    const int* maskb = mask + b * 2048;

    // mask bitmask: bit i (= kt*8 + ni) covers column i*16 + ln
    unsigned long long mb0 = 0ull, mb1 = 0ull;
#pragma unroll 8
    for (int i = 0; i < 64; ++i) {
        if (maskb[i * 16 + ln] != 0)        mb0 |= (1ull << i);
        if (maskb[(i + 64) * 16 + ln] != 0) mb1 |= (1ull << i);
    }

    // Q fragments live in registers for the whole kernel
    bf16x8 aq[2][2];
#pragma unroll
    for (int mi = 0; mi < 2; ++mi)
#pragma unroll
        for (int ks = 0; ks < 2; ++ks)
            aq[mi][ks] = *(const bf16x8*)(qbase + (mi * 16 + ln) * 64 + ks * 32 + qd * 8);

    float lsum[2][4];
#pragma unroll
    for (int mi = 0; mi < 2; ++mi)
#pragma unroll
        for (int r = 0; r < 4; ++r) lsum[mi][r] = 0.f;

    f32x4 zero4 = {0.f, 0.f, 0.f, 0.f};

    // ================= pass 1: row sums (fixed max) =================
    for (int kt = 0; kt < 16; ++kt) {
#pragma unroll
        for (int it = 0; it < 4; ++it) {
            int idx = tid + it * 256;
            int r = idx >> 3, c8 = idx & 7;
            *(uint4*)(Ks + r * LKS + c8 * 8) =
                *(const uint4*)(kbase + (size_t)(kt * 128 + r) * 64 + c8 * 8);
        }
        __syncthreads();

        f32x4 s[2][8];
#pragma unroll
        for (int mi = 0; mi < 2; ++mi)
#pragma unroll
            for (int ni = 0; ni < 8; ++ni) s[mi][ni] = zero4;
#pragma unroll
        for (int ks = 0; ks < 2; ++ks) {
            bf16x8 bk[8];
#pragma unroll
            for (int ni = 0; ni < 8; ++ni)
                bk[ni] = *(const bf16x8*)(Ks + (ni * 16 + ln) * LKS + ks * 32 + qd * 8);
#pragma unroll
            for (int mi = 0; mi < 2; ++mi)
#pragma unroll
                for (int ni = 0; ni < 8; ++ni)
                    s[mi][ni] = __builtin_amdgcn_mfma_f32_16x16x32_bf16(
                        aq[mi][ks], bk[ni], s[mi][ni], 0, 0, 0);
        }

        unsigned int mk = (unsigned int)(((kt < 8) ? mb0 : mb1) >> ((kt & 7) * 8)) & 0xffu;
        float keepf[8];
#pragma unroll
        for (int ni = 0; ni < 8; ++ni) keepf[ni] = ((mk >> ni) & 1u) ? 1.0f : 0.0f;

#pragma unroll
        for (int mi = 0; mi < 2; ++mi)
#pragma unroll
            for (int r = 0; r < 4; ++r) {
                float acc = 0.f;
#pragma unroll
                for (int ni = 0; ni < 8; ++ni)
                    acc += keepf[ni] * exp2f(s[mi][ni][r]);
                lsum[mi][r] += acc;
            }
        __syncthreads();
    }

    // single cross-lane reduce at the end
    float rl[2][4];
#pragma unroll
    for (int mi = 0; mi < 2; ++mi)
#pragma unroll
        for (int r = 0; r < 4; ++r) {
            float ss = lsum[mi][r];
            ss += __shfl_xor(ss, 1);
            ss += __shfl_xor(ss, 2);
            ss += __shfl_xor(ss, 4);
            ss += __shfl_xor(ss, 8);
            rl[mi][r] = 1.0f / ss;
        }

    f32x4 oacc[2][4];
#pragma unroll
    for (int mi = 0; mi < 2; ++mi)
#pragma unroll
        for (int nt = 0; nt < 4; ++nt) oacc[mi][nt] = zero4;

    float* attnb = attn + (size_t)bh * 2048 * 2048;

    // ================= pass 2: attn write + P @ V =================
    for (int kt = 0; kt < 16; ++kt) {
#pragma unroll
        for (int it = 0; it < 4; ++it) {
            int idx = tid + it * 256;
            int r = idx >> 3, c8 = idx & 7;
            *(uint4*)(Ks + r * LKS + c8 * 8) =
                *(const uint4*)(kbase + (size_t)(kt * 128 + r) * 64 + c8 * 8);
        }
        // V^T staging: coalesced global reads (consecutive dk), b64 LDS writes
#pragma unroll
        for (int it = 0; it < 4; ++it) {
            int idx = tid + it * 256;             // 1024 units: (ro 0..15, dk 0..63)
            int dk = idx & 63, ro = idx >> 6;
            unsigned short tmp[8];
#pragma unroll
            for (int j = 0; j < 8; ++j)
                tmp[j] = vbase[(size_t)(kt * 128 + ro * 8 + j) * 64 + dk];
            us4 w0 = { tmp[0], tmp[1], tmp[2], tmp[3] };
            us4 w1 = { tmp[4], tmp[5], tmp[6], tmp[7] };
            *(us4*)(Vts + dk * LVS + ro * 8) = w0;
            *(us4*)(Vts + dk * LVS + ro * 8 + 4) = w1;
        }
        __syncthreads();

        f32x4 s[2][8];
#pragma unroll
        for (int mi = 0; mi < 2; ++mi)
#pragma unroll
            for (int ni = 0; ni < 8; ++ni) s[mi][ni] = zero4;
#pragma unroll
        for (int ks = 0; ks < 2; ++ks) {
            bf16x8 bk[8];
#pragma unroll
            for (int ni = 0; ni < 8; ++ni)
                bk[ni] = *(const bf16x8*)(Ks + (ni * 16 + ln) * LKS + ks * 32 + qd * 8);
#pragma unroll
            for (int mi = 0; mi < 2; ++mi)
#pragma unroll
                for (int ni = 0; ni < 8; ++ni)
                    s[mi][ni] = __builtin_amdgcn_mfma_f32_16x16x32_bf16(
                        aq[mi][ks], bk[ni], s[mi][ni], 0, 0, 0);
        }

        unsigned int mk = (unsigned int)(((kt < 8) ? mb0 : mb1) >> ((kt & 7) * 8)) & 0xffu;
        float keepf[8];
#pragma unroll
        for (int ni = 0; ni < 8; ++ni) keepf[ni] = ((mk >> ni) & 1u) ? 1.0f : 0.0f;

        // P~ = exp2(s)*keep -> Ps (bf16, unnormalized); attn = P~ / l (fp32,
        // straight from registers, no LDS roundtrip)
#pragma unroll
        for (int mi = 0; mi < 2; ++mi)
#pragma unroll
            for (int r = 0; r < 4; ++r) {
                int prow = wid * 32 + mi * 16 + qd * 4 + r;
                float rr = rl[mi][r];
                float* arow = attnb + (size_t)(qt * 128 + prow) * 2048 + kt * 128 + ln;
                unsigned short* psrow = Ps + prow * LPS + ln;
#pragma unroll
                for (int np = 0; np < 4; ++np) {
                    float e0 = exp2f(s[mi][2 * np][r]) * keepf[2 * np];
                    float e1 = exp2f(s[mi][2 * np + 1][r]) * keepf[2 * np + 1];
                    unsigned int pk = cvt_pk_bf16(e0, e1);
                    psrow[(2 * np) * 16]     = (unsigned short)(pk & 0xffffu);
                    psrow[(2 * np + 1) * 16] = (unsigned short)(pk >> 16);
                    arow[(2 * np) * 16]     = e0 * rr;
                    arow[(2 * np + 1) * 16] = e1 * rr;
                }
            }
        __syncthreads();   // Ps visible to PV (removal is a later A/B)

        // P @ V  (A from Ps own-wave rows, B from Vts)
#pragma unroll
        for (int ks = 0; ks < 4; ++ks) {
            bf16x8 ap[2], bv[4];
#pragma unroll
            for (int mi = 0; mi < 2; ++mi)
                ap[mi] = *(const bf16x8*)(Ps + (wid * 32 + mi * 16 + ln) * LPS + ks * 32 + qd * 8);
#pragma unroll
            for (int nt = 0; nt < 4; ++nt)
                bv[nt] = *(const bf16x8*)(Vts + (nt * 16 + ln) * LVS + ks * 32 + qd * 8);
#pragma unroll
            for (int mi = 0; mi < 2; ++mi)
#pragma unroll
                for (int nt = 0; nt < 4; ++nt)
                    oacc[mi][nt] = __builtin_amdgcn_mfma_f32_16x16x32_bf16(
                        ap[mi], bv[nt], oacc[mi][nt], 0, 0, 0);
        }
        __syncthreads();
    }

    // ---- epilogue: O = (P~ @ V) * (1/l) -> Og (B,L,D) bf16 ----
    const int q0 = qt * 128 + wid * 32;
#pragma unroll
    for (int mi = 0; mi < 2; ++mi)
#pragma unroll
        for (int nt = 0; nt < 4; ++nt)
#pragma unroll
            for (int r = 0; r < 4; ++r) {
                int qrow = q0 + mi * 16 + qd * 4 + r;
                int dk = nt * 16 + ln;
                size_t oi = ((size_t)b * 2048 + qrow) * 1024 + h * 64 + dk;
                Og[oi] = f2bf(oacc[mi][nt][r] * rl[mi][r]);
            }
}

// ---------------------------------------------------------------------------
extern "C" void kernel_launch(void* const* d_in, const int* in_sizes, int n_in,
                              void* d_out, int out_size, void* d_ws, size_t ws_size,
                              hipStream_t stream)
{
    (void)in_sizes; (void)n_in; (void)out_size; (void)ws_size;
    const float* q     = (const float*)d_in[0];
    const float* k     = (const float*)d_in[1];
    const float* v     = (const float*)d_in[2];
    const float* sem   = (const float*)d_in[3];
    const int*   mask  = (const int*)d_in[4];
    const float* w_q   = (const float*)d_in[5];
    const float* b_q   = (const float*)d_in[6];
    const float* w_k   = (const float*)d_in[7];
    const float* b_k   = (const float*)d_in[8];
    const float* w_v   = (const float*)d_in[9];
    const float* b_v   = (const float*)d_in[10];
    const float* w_sem = (const float*)d_in[11];
    const float* b_sem = (const float*)d_in[12];
    const float* w_out = (const float*)d_in[13];
    const float* b_out = (const float*)d_in[14];

    const size_t NE = (size_t)8192 * 1024;
    unsigned short* semh = (unsigned short*)d_ws;
    unsigned short* qh   = semh + NE;
    unsigned short* kh   = qh + NE;
    unsigned short* vh   = kh + NE;
    unsigned short* Og   = vh + NE;

    float* outp  = (float*)d_out;
    float* attnp = outp + NE;

    dim3 gg(8, 64), bb(256);
    // sem projection (head layout)
    hipLaunchKernelGGL((gemm_nt_kernel<0, 0>), gg, bb, 0, stream,
                       (const void*)sem, w_sem, b_sem, (const unsigned short*)nullptr,
                       (void*)semh, 1.0f);
    // q projection, scaled by log2(e)/sqrt(64) so attn softmax can use exp2
    hipLaunchKernelGGL((gemm_nt_kernel<0, 0>), gg, bb, 0, stream,
                       (const void*)q, w_q, b_q, (const unsigned short*)nullptr,
                       (void*)qh, 0.18033688011112042f);
    // k projection + sem
    hipLaunchKernelGGL((gemm_nt_kernel<0, 0>), gg, bb, 0, stream,
                       (const void*)k, w_k, b_k, semh, (void*)kh, 1.0f);
    // v projection + sem
    hipLaunchKernelGGL((gemm_nt_kernel<0, 0>), gg, bb, 0, stream,
                       (const void*)v, w_v, b_v, semh, (void*)vh, 1.0f);
    // fused attention
    hipLaunchKernelGGL(attn_kernel, dim3(16, 64), bb, 0, stream,
                       qh, kh, vh, mask, attnp, Og);
    // output projection (fp32 out)
    hipLaunchKernelGGL((gemm_nt_kernel<1, 1>), gg, bb, 0, stream,
                       (const void*)Og, w_out, b_out, (const unsigned short*)nullptr,
                       (void*)outp, 1.0f);
}